// Round 5
// baseline (611.298 us; speedup 1.0000x reference)
//
#include <hip/hip_runtime.h>
#include <cstdint>
#include <cstddef>

// ---------------------------------------------------------------------------
// Shapes: x (2,8,96,96,192) fp32 ; windows 1x8x8 ; NH=2 ; hd=96 ; L=512 ; MLP 768
// tokens N = 147456 ; Bp = 288 ; Dn = 8
// ---------------------------------------------------------------------------

typedef float   f32x4  __attribute__((ext_vector_type(4)));
typedef __bf16  bf16x8 __attribute__((ext_vector_type(8)));
typedef unsigned int   u32x4  __attribute__((ext_vector_type(4)));
typedef unsigned short u16x4  __attribute__((ext_vector_type(4)));

#define DEVI __device__ __forceinline__

DEVI float bf2f(unsigned short u) {
    union { unsigned int i; float f; } v; v.i = ((unsigned int)u) << 16; return v.f;
}
DEVI unsigned short f2bf(float f) {
    unsigned int u = __builtin_bit_cast(unsigned int, f);
    unsigned int r = u + 0x7fffu + ((u >> 16) & 1u);   // RNE
    return (unsigned short)(r >> 16);
}

// async global->LDS, 16B per lane; LDS dest is wave-uniform base + lane*16
typedef __attribute__((address_space(3))) unsigned char       lds_u8;
typedef __attribute__((address_space(1))) const unsigned char g_u8;
DEVI void gl_lds16(const void* g, void* l) {
    __builtin_amdgcn_global_load_lds((g_u8*)g, (lds_u8*)l, 16, 0, 0);
}

// ---------------------------------------------------------------------------
// K0: convert + pad weights fp32 -> bf16.
// ---------------------------------------------------------------------------
__global__ __launch_bounds__(256) void k_wconv(const float* __restrict__ wqkv,
                                               const float* __restrict__ wout,
                                               const float* __restrict__ wfc1,
                                               const float* __restrict__ wfc2,
                                               unsigned short* __restrict__ oq,
                                               unsigned short* __restrict__ oo,
                                               unsigned short* __restrict__ o1,
                                               unsigned short* __restrict__ o2) {
    int i = blockIdx.x * 256 + threadIdx.x;
    if (i < 122880) {                       // [640][192]
        int r = i / 192;
        oq[i] = (r < 576) ? f2bf(wqkv[i]) : (unsigned short)0;
    } else if (i < 172032) {                // [256][192]
        int j = i - 122880; int r = j / 192;
        oo[j] = (r < 192) ? f2bf(wout[j]) : (unsigned short)0;
    } else if (i < 319488) {                // [768][192]
        int j = i - 172032;
        o1[j] = f2bf(wfc1[j]);
    } else if (i < 516096) {                // [256][768]
        int j = i - 319488; int r = j / 768;
        o2[j] = (r < 192) ? f2bf(wfc2[j]) : (unsigned short)0;
    }
}

// ---------------------------------------------------------------------------
// K1: LayerNorm(norm3) + window partition -> h bf16 [288][512][192]
// ---------------------------------------------------------------------------
__global__ __launch_bounds__(256) void k_ln3(const float* __restrict__ x,
                                             const float* __restrict__ g,
                                             const float* __restrict__ bsh,
                                             unsigned short* __restrict__ h) {
    int w = threadIdx.x >> 6, lane = threadIdx.x & 63;
    int token = blockIdx.x * 4 + w;
    const float* xp = x + (size_t)token * 192;
    float v0 = xp[lane], v1 = xp[lane + 64], v2 = xp[lane + 128];
    float s = v0 + v1 + v2;
#pragma unroll
    for (int off = 32; off; off >>= 1) s += __shfl_xor(s, off);
    float mean = s * (1.f / 192.f);
    float d0 = v0 - mean, d1 = v1 - mean, d2 = v2 - mean;
    float q = d0 * d0 + d1 * d1 + d2 * d2;
#pragma unroll
    for (int off = 32; off; off >>= 1) q += __shfl_xor(q, off);
    float rs = rsqrtf(q * (1.f / 192.f) + 1e-5f);
    int b  = token / (8 * 96 * 96);
    int r0 = token - b * (8 * 96 * 96);
    int d  = r0 / (96 * 96);
    int r1 = r0 - d * (96 * 96);
    int hh = r1 / 96;
    int ww = r1 - hh * 96;
    int bp = b * 144 + (hh >> 3) * 12 + (ww >> 3);
    int l  = d * 64 + (hh & 7) * 8 + (ww & 7);
    unsigned short* hp = h + ((size_t)bp * 512 + l) * 192;
    hp[lane]       = f2bf(d0 * rs * g[lane]       + bsh[lane]);
    hp[lane + 64]  = f2bf(d1 * rs * g[lane + 64]  + bsh[lane + 64]);
    hp[lane + 128] = f2bf(d2 * rs * g[lane + 128] + bsh[lane + 128]);
}

// ---------------------------------------------------------------------------
// K5: LayerNorm(norm4) on bf16 y, natural layout -> xn4 bf16.
// 8 rows/block, 32 lanes per row, u32-packed loads/stores.
// ---------------------------------------------------------------------------
__global__ __launch_bounds__(256) void k_ln4b(const unsigned short* __restrict__ yb,
                                              const float* __restrict__ g,
                                              const float* __restrict__ bsh,
                                              unsigned short* __restrict__ xn) {
    int sub = threadIdx.x >> 5, tl = threadIdx.x & 31;
    size_t row = (size_t)blockIdx.x * 8 + sub;
    const unsigned int* rp = reinterpret_cast<const unsigned int*>(yb + row * 192);
    float v[6];
#pragma unroll
    for (int j = 0; j < 3; j++) {
        unsigned int w = rp[tl + 32 * j];
        v[2 * j]     = bf2f((unsigned short)(w & 0xffffu));
        v[2 * j + 1] = bf2f((unsigned short)(w >> 16));
    }
    float s = v[0] + v[1] + v[2] + v[3] + v[4] + v[5];
#pragma unroll
    for (int off = 1; off < 32; off <<= 1) s += __shfl_xor(s, off);
    float mean = s * (1.f / 192.f);
    float q = 0.f;
#pragma unroll
    for (int j = 0; j < 6; j++) { v[j] -= mean; q += v[j] * v[j]; }
#pragma unroll
    for (int off = 1; off < 32; off <<= 1) q += __shfl_xor(q, off);
    float rs = rsqrtf(q * (1.f / 192.f) + 1e-5f);
    unsigned int* op = reinterpret_cast<unsigned int*>(xn + row * 192);
#pragma unroll
    for (int j = 0; j < 3; j++) {
        int c = (tl + 32 * j) * 2;
        unsigned short lo = f2bf(v[2 * j]     * rs * g[c]     + bsh[c]);
        unsigned short hi = f2bf(v[2 * j + 1] * rs * g[c + 1] + bsh[c + 1]);
        op[tl + 32 * j] = ((unsigned int)hi << 16) | lo;
    }
}

// ---------------------------------------------------------------------------
// K2: 128x128-tile GEMM, 2-phase double-buffered pipeline (T3-minimum):
// stage tile t+1 (global_load_lds, 16B, XOR-swizzled source) BEFORE computing
// tile t; one barrier per tile. LDS 2 x (16KB A + 16KB B) = 64KB.
// EPI 0: qkv -> qk (q scaled) + vt (v transposed, packed 8B)
// EPI 1: out_proj + window-reverse + x residual -> ybf bf16 (natural layout)
// EPI 2: fc1 + exact gelu -> hidden bf16
// EPI 3: fc2 + ybf residual -> out fp32 (d_out)
// ---------------------------------------------------------------------------
template <int EPI, int K>
__global__ __launch_bounds__(256) void k_gemm128(const unsigned short* __restrict__ A,
                                                 const unsigned short* __restrict__ Bw,
                                                 const float* __restrict__ bias,
                                                 unsigned short* __restrict__ outb,
                                                 unsigned short* __restrict__ vt,
                                                 float* __restrict__ outf,
                                                 const float* __restrict__ res,
                                                 const unsigned short* __restrict__ resb) {
    __shared__ unsigned short As[2][128 * 64];
    __shared__ unsigned short Bs[2][128 * 64];
    const int tid = threadIdx.x;
    // XCD-aware swizzle of the flat block id (nwg % 8 == 0)
    const int nwg = gridDim.x * gridDim.y;
    const int flat = blockIdx.y * gridDim.x + blockIdx.x;
    const int swz = (flat & 7) * (nwg >> 3) + (flat >> 3);
    const int bx = swz % gridDim.x, by = swz / gridDim.x;
    const int row0 = by * 128, col0 = bx * 128;
    const int wv = tid >> 6, lane = tid & 63, lr = lane & 15, lg = lane >> 4;
    const int wr = wv >> 1, wc = wv & 1;
    const int sr = lane >> 3, sc = lane & 7;     // staging: 8 rows x 8 chunks / inst
    f32x4 acc[4][4] = {};

    auto stage = [&](int t, int buf) {
        int k0 = t * 64;
#pragma unroll
        for (int i = 0; i < 4; i++) {
            int gq = wv * 4 + i;                 // 1KB group = rows [gq*8, gq*8+8)
            int r = gq * 8 + sr;
            int j = sc ^ (r & 7);                // swizzled source chunk
            gl_lds16(A + (size_t)(row0 + r) * K + k0 + j * 8, &As[buf][gq * 512]);
        }
#pragma unroll
        for (int i = 0; i < 4; i++) {
            int gq = wv * 4 + i;
            int r = gq * 8 + sr;
            int j = sc ^ (r & 7);
            gl_lds16(Bw + (size_t)(col0 + r) * K + k0 + j * 8, &Bs[buf][gq * 512]);
        }
    };

    const int NT = K / 64;
    stage(0, 0);
    __syncthreads();
    for (int t = 0; t < NT; ++t) {
        int cur = t & 1;
        if (t + 1 < NT) stage(t + 1, cur ^ 1);   // prefetch lands during compute
#pragma unroll
        for (int kk = 0; kk < 64; kk += 32) {
            bf16x8 af[4], bf[4];
#pragma unroll
            for (int m = 0; m < 4; m++) {
                int r = wr * 64 + m * 16 + lr;
                int j = ((kk >> 3) + lg) ^ (r & 7);
                af[m] = __builtin_bit_cast(bf16x8,
                    *reinterpret_cast<const u32x4*>(&As[cur][r * 64 + j * 8]));
            }
#pragma unroll
            for (int n = 0; n < 4; n++) {
                int r = wc * 64 + n * 16 + lr;
                int j = ((kk >> 3) + lg) ^ (r & 7);
                bf[n] = __builtin_bit_cast(bf16x8,
                    *reinterpret_cast<const u32x4*>(&Bs[cur][r * 64 + j * 8]));
            }
#pragma unroll
            for (int m = 0; m < 4; m++)
#pragma unroll
                for (int n = 0; n < 4; n++)
                    acc[m][n] = __builtin_amdgcn_mfma_f32_16x16x32_bf16(af[m], bf[n], acc[m][n], 0, 0, 0);
        }
        __syncthreads();   // drains vmcnt(0): prefetched tile visible; readers done
    }

#pragma unroll
    for (int m = 0; m < 4; m++) {
#pragma unroll
        for (int n = 0; n < 4; n++) {
            int col  = col0 + wc * 64 + n * 16 + lr;
            int rowb = row0 + wr * 64 + m * 16 + lg * 4;
            if constexpr (EPI == 0) {
                if (col < 384) {
                    float b = bias[col];
                    float sc2 = (col < 192) ? 0.1020620726159658f : 1.f;  // 1/sqrt(96) on q
#pragma unroll
                    for (int rr = 0; rr < 4; rr++)
                        outb[(size_t)(rowb + rr) * 384 + col] = f2bf((acc[m][n][rr] + b) * sc2);
                } else if (col < 576) {
                    float b = bias[col];
                    int head = (col >= 480) ? 1 : 0;
                    int d = col - 384 - head * 96;
                    int bp = rowb >> 9, tok = rowb & 511;
                    u16x4 pk = { f2bf(acc[m][n][0] + b), f2bf(acc[m][n][1] + b),
                                 f2bf(acc[m][n][2] + b), f2bf(acc[m][n][3] + b) };
                    *reinterpret_cast<u16x4*>(vt + ((size_t)(bp * 2 + head) * 96 + d) * 512 + tok) = pk;
                }
            } else if constexpr (EPI == 1) {
                if (col < 192) {
                    float b = bias[col];
#pragma unroll
                    for (int rr = 0; rr < 4; rr++) {
                        int nrow = rowb + rr;
                        int bp = nrow >> 9, l = nrow & 511;
                        int bb = bp / 144, p = bp - bb * 144;
                        int hn = p / 12, wn = p - hn * 12;
                        int dn = l >> 6, t_ = l & 63;
                        size_t tok = ((size_t)((bb * 8 + dn) * 96 + hn * 8 + (t_ >> 3)) * 96 + wn * 8 + (t_ & 7));
                        size_t idx = tok * 192 + col;
                        outb[idx] = f2bf(res[idx] + acc[m][n][rr] + b);   // ybf bf16
                    }
                }
            } else if constexpr (EPI == 2) {
                float b = bias[col];
#pragma unroll
                for (int rr = 0; rr < 4; rr++) {
                    float v = acc[m][n][rr] + b;
                    float gz = 0.5f * v * (1.f + erff(v * 0.70710678118654752f));
                    outb[(size_t)(rowb + rr) * 768 + col] = f2bf(gz);
                }
            } else {
                if (col < 192) {
                    float b = bias[col];
#pragma unroll
                    for (int rr = 0; rr < 4; rr++) {
                        size_t idx = (size_t)(rowb + rr) * 192 + col;
                        outf[idx] = bf2f(resb[idx]) + acc[m][n][rr] + b;
                    }
                }
            }
        }
    }
}

// ---------------------------------------------------------------------------
// K3: block-causal attention, dnq-paired 8-wave WG (unchanged from round 4).
// ---------------------------------------------------------------------------
__global__ __launch_bounds__(512) void k_attn(const unsigned short* __restrict__ qk,
                                              const unsigned short* __restrict__ vt,
                                              unsigned short* __restrict__ aout) {
    __shared__ unsigned short Ks[64][104];
    __shared__ unsigned short Vs[96][72];
    __shared__ unsigned short Ps[8][16][72];

    int bid = (blockIdx.x & 7) * 288 + (blockIdx.x >> 3);   // 2304 % 8 == 0
    int bp = bid >> 3, rest = bid & 7, head = rest >> 2, pr = rest & 3;
    int tid = threadIdx.x, wv = tid >> 6, lane = tid & 63;
    int lr = lane & 15, lg = lane >> 4;
    int wq = wv & 3, wt = wv >> 2;
    int nk = 2 * pr + 2;

    size_t qrow0 = (size_t)bp * 512 + (size_t)(2 * pr + wt) * 64;
    const unsigned short* vbase = vt + (size_t)(bp * 2 + head) * 96 * 512;
    size_t krowb = (size_t)bp * 512;

    bf16x8 qf[3];
    {
        const unsigned short* qp = qk + (qrow0 + wq * 16 + lr) * 384 + head * 96 + lg * 8;
#pragma unroll
        for (int ks = 0; ks < 3; ks++)
            qf[ks] = __builtin_bit_cast(bf16x8, *reinterpret_cast<const u32x4*>(qp + ks * 32));
    }

    f32x4 o[6] = {};
    float m_ = -1e30f, lsum = 0.f;

    u32x4 sreg[3];
    auto issue = [&](int dnk) {
#pragma unroll
        for (int i = 0; i < 3; i++) {
            int c = tid + i * 512;
            if (c < 768) {
                int r = c / 12, cc = c - r * 12;
                sreg[i] = *reinterpret_cast<const u32x4*>(
                    qk + (krowb + dnk * 64 + r) * 384 + 192 + head * 96 + cc * 8);
            } else {
                int c2 = c - 768; int d = c2 >> 3, tb = c2 & 7;
                sreg[i] = *reinterpret_cast<const u32x4*>(
                    vbase + (size_t)d * 512 + dnk * 64 + tb * 8);
            }
        }
    };
    auto commit = [&]() {
#pragma unroll
        for (int i = 0; i < 3; i++) {
            int c = tid + i * 512;
            if (c < 768) {
                int r = c / 12, cc = c - r * 12;
                *reinterpret_cast<u32x4*>(&Ks[r][cc * 8]) = sreg[i];
            } else {
                int c2 = c - 768; int d = c2 >> 3, tb = c2 & 7;
                *reinterpret_cast<u32x4*>(&Vs[d][tb * 8]) = sreg[i];
            }
        }
    };

    issue(0);
    for (int dnk = 0; dnk < nk; ++dnk) {
        commit();
        __syncthreads();
        if (dnk + 1 < nk) issue(dnk + 1);
        if (wt == 1 || dnk < nk - 1) {
            f32x4 st[4] = {};
#pragma unroll
            for (int ks = 0; ks < 3; ks++) {
#pragma unroll
                for (int ct = 0; ct < 4; ct++) {
                    bf16x8 kf = __builtin_bit_cast(bf16x8,
                        *reinterpret_cast<const u32x4*>(&Ks[ct * 16 + lr][ks * 32 + lg * 8]));
                    st[ct] = __builtin_amdgcn_mfma_f32_16x16x32_bf16(kf, qf[ks], st[ct], 0, 0, 0);
                }
            }
            float mx = st[0][0];
#pragma unroll
            for (int ct = 0; ct < 4; ct++)
#pragma unroll
                for (int rr = 0; rr < 4; rr++) mx = fmaxf(mx, st[ct][rr]);
            mx = fmaxf(mx, __shfl_xor(mx, 16));
            mx = fmaxf(mx, __shfl_xor(mx, 32));
            float mnew = fmaxf(m_, mx);
            float corr = __expf(m_ - mnew);
            m_ = mnew;
            float ps = 0.f;
#pragma unroll
            for (int ct = 0; ct < 4; ct++) {
                u16x4 pk;
#pragma unroll
                for (int rr = 0; rr < 4; rr++) {
                    float pv = __expf(st[ct][rr] - mnew);
                    ps += pv;
                    pk[rr] = f2bf(pv);
                }
                *reinterpret_cast<u16x4*>(&Ps[wv][lr][ct * 16 + lg * 4]) = pk;
            }
            ps += __shfl_xor(ps, 16);
            ps += __shfl_xor(ps, 32);
            lsum = lsum * corr + ps;
#pragma unroll
            for (int rr = 0; rr < 4; rr++) {
                float cr = __shfl(corr, (lane & 48) | (lg * 4 + rr));
#pragma unroll
                for (int nf = 0; nf < 6; nf++) o[nf][rr] *= cr;
            }
#pragma unroll
            for (int kk = 0; kk < 2; kk++) {
                bf16x8 pf = __builtin_bit_cast(bf16x8,
                    *reinterpret_cast<const u32x4*>(&Ps[wv][lr][kk * 32 + lg * 8]));
#pragma unroll
                for (int nf = 0; nf < 6; nf++) {
                    bf16x8 vf = __builtin_bit_cast(bf16x8,
                        *reinterpret_cast<const u32x4*>(&Vs[nf * 16 + lr][kk * 32 + lg * 8]));
                    o[nf] = __builtin_amdgcn_mfma_f32_16x16x32_bf16(pf, vf, o[nf], 0, 0, 0);
                }
            }
        }
        __syncthreads();
    }

#pragma unroll
    for (int rr = 0; rr < 4; rr++) {
        float li = __shfl(lsum, (lane & 48) | (lg * 4 + rr));
        float inv = 1.f / li;
        size_t row = qrow0 + wq * 16 + lg * 4 + rr;
#pragma unroll
        for (int nf = 0; nf < 6; nf++)
            aout[row * 192 + head * 96 + nf * 16 + lr] = f2bf(o[nf][rr] * inv);
    }
}

// ---------------------------------------------------------------------------
// Launcher. ws arena (~340.8 MB):
//   [0, 113.2M)        qk bf16 [147456][384]   } hidden [147456][768]
//   [113.2M, 169.9M)   vt bf16 [576][96][512]  }   aliases [0, 226.5M)
//   [169.9M, 226.5M)   h  bf16 [147456][192]   }   at fc1/fc2 time
//   [226.5M, 283.1M)   attn bf16 ; xn4 aliases it after out_proj
//   [283.1M, 284.2M)   bf16 padded weights
//   [284.2M, 340.8M)   ybf bf16 [147456][192]  (x + attn residual)
// d_out written only by fc2 (fully rewritten each call => replay safe).
// ---------------------------------------------------------------------------
extern "C" void kernel_launch(void* const* d_in, const int* in_sizes, int n_in,
                              void* d_out, int out_size, void* d_ws, size_t ws_size,
                              hipStream_t stream) {
    const float* x    = (const float*)d_in[0];
    const float* n3g  = (const float*)d_in[1];
    const float* n3b  = (const float*)d_in[2];
    const float* wqkv = (const float*)d_in[3];
    const float* bqkv = (const float*)d_in[4];
    const float* wout = (const float*)d_in[5];
    const float* bout = (const float*)d_in[6];
    const float* n4g  = (const float*)d_in[7];
    const float* n4b  = (const float*)d_in[8];
    const float* wfc1 = (const float*)d_in[9];
    const float* bfc1 = (const float*)d_in[10];
    const float* wfc2 = (const float*)d_in[11];
    const float* bfc2 = (const float*)d_in[12];
    float* out = (float*)d_out;

    char* ws = (char*)d_ws;
    unsigned short* qk     = (unsigned short*)(ws + 0);
    unsigned short* vt     = (unsigned short*)(ws + 113246208);
    unsigned short* h      = (unsigned short*)(ws + 169869312);
    unsigned short* attn   = (unsigned short*)(ws + 226492416);
    unsigned short* xn4    = (unsigned short*)(ws + 226492416);   // alias attn
    unsigned short* hidden = (unsigned short*)(ws + 0);           // alias qk+vt+h
    unsigned short* wq_bf  = (unsigned short*)(ws + 283115520);
    unsigned short* wo_bf  = (unsigned short*)(ws + 283361280);
    unsigned short* w1_bf  = (unsigned short*)(ws + 283459584);
    unsigned short* w2_bf  = (unsigned short*)(ws + 283754496);
    unsigned short* ybf    = (unsigned short*)(ws + 284147712);

    k_wconv<<<2016, 256, 0, stream>>>(wqkv, wout, wfc1, wfc2, wq_bf, wo_bf, w1_bf, w2_bf);
    k_ln3<<<36864, 256, 0, stream>>>(x, n3g, n3b, h);
    k_gemm128<0, 192><<<dim3(5, 1152), 256, 0, stream>>>(h, wq_bf, bqkv, qk, vt, nullptr, nullptr, nullptr);
    k_attn<<<2304, 512, 0, stream>>>(qk, vt, attn);
    k_gemm128<1, 192><<<dim3(2, 1152), 256, 0, stream>>>(attn, wo_bf, bout, ybf, nullptr, nullptr, x, nullptr);
    k_ln4b<<<18432, 256, 0, stream>>>(ybf, n4g, n4b, xn4);
    k_gemm128<2, 192><<<dim3(6, 1152), 256, 0, stream>>>(xn4, w1_bf, bfc1, hidden, nullptr, nullptr, nullptr, nullptr);
    k_gemm128<3, 768><<<dim3(2, 1152), 256, 0, stream>>>(hidden, w2_bf, bfc2, nullptr, nullptr, out, nullptr, ybf);
}

// Round 6
// 587.124 us; speedup vs baseline: 1.0412x; 1.0412x over previous
//
#include <hip/hip_runtime.h>
#include <cstdint>
#include <cstddef>

// ---------------------------------------------------------------------------
// Shapes: x (2,8,96,96,192) fp32 ; windows 1x8x8 ; NH=2 ; hd=96 ; L=512 ; MLP 768
// tokens N = 147456 ; Bp = 288 ; Dn = 8
// ---------------------------------------------------------------------------

typedef float   f32x4  __attribute__((ext_vector_type(4)));
typedef __bf16  bf16x8 __attribute__((ext_vector_type(8)));
typedef unsigned int   u32x4  __attribute__((ext_vector_type(4)));
typedef unsigned short u16x4  __attribute__((ext_vector_type(4)));

#define DEVI __device__ __forceinline__

DEVI float bf2f(unsigned short u) {
    union { unsigned int i; float f; } v; v.i = ((unsigned int)u) << 16; return v.f;
}
DEVI unsigned short f2bf(float f) {
    unsigned int u = __builtin_bit_cast(unsigned int, f);
    unsigned int r = u + 0x7fffu + ((u >> 16) & 1u);   // RNE
    return (unsigned short)(r >> 16);
}

// async global->LDS, 16B per lane; LDS dest is wave-uniform base + lane*16
typedef __attribute__((address_space(3))) unsigned char       lds_u8;
typedef __attribute__((address_space(1))) const unsigned char g_u8;
DEVI void gl_lds16(const void* g, void* l) {
    __builtin_amdgcn_global_load_lds((g_u8*)g, (lds_u8*)l, 16, 0, 0);
}

// ---------------------------------------------------------------------------
// K0: convert + pad weights fp32 -> bf16.
// ---------------------------------------------------------------------------
__global__ __launch_bounds__(256) void k_wconv(const float* __restrict__ wqkv,
                                               const float* __restrict__ wout,
                                               const float* __restrict__ wfc1,
                                               const float* __restrict__ wfc2,
                                               unsigned short* __restrict__ oq,
                                               unsigned short* __restrict__ oo,
                                               unsigned short* __restrict__ o1,
                                               unsigned short* __restrict__ o2) {
    int i = blockIdx.x * 256 + threadIdx.x;
    if (i < 122880) {                       // [640][192]
        int r = i / 192;
        oq[i] = (r < 576) ? f2bf(wqkv[i]) : (unsigned short)0;
    } else if (i < 172032) {                // [256][192]
        int j = i - 122880; int r = j / 192;
        oo[j] = (r < 192) ? f2bf(wout[j]) : (unsigned short)0;
    } else if (i < 319488) {                // [768][192]
        int j = i - 172032;
        o1[j] = f2bf(wfc1[j]);
    } else if (i < 516096) {                // [256][768]
        int j = i - 319488; int r = j / 768;
        o2[j] = (r < 192) ? f2bf(wfc2[j]) : (unsigned short)0;
    }
}

// ---------------------------------------------------------------------------
// K1: LayerNorm(norm3) + window partition -> h bf16 [288][512][192]
// ---------------------------------------------------------------------------
__global__ __launch_bounds__(256) void k_ln3(const float* __restrict__ x,
                                             const float* __restrict__ g,
                                             const float* __restrict__ bsh,
                                             unsigned short* __restrict__ h) {
    int w = threadIdx.x >> 6, lane = threadIdx.x & 63;
    int token = blockIdx.x * 4 + w;
    const float* xp = x + (size_t)token * 192;
    float v0 = xp[lane], v1 = xp[lane + 64], v2 = xp[lane + 128];
    float s = v0 + v1 + v2;
#pragma unroll
    for (int off = 32; off; off >>= 1) s += __shfl_xor(s, off);
    float mean = s * (1.f / 192.f);
    float d0 = v0 - mean, d1 = v1 - mean, d2 = v2 - mean;
    float q = d0 * d0 + d1 * d1 + d2 * d2;
#pragma unroll
    for (int off = 32; off; off >>= 1) q += __shfl_xor(q, off);
    float rs = rsqrtf(q * (1.f / 192.f) + 1e-5f);
    int b  = token / (8 * 96 * 96);
    int r0 = token - b * (8 * 96 * 96);
    int d  = r0 / (96 * 96);
    int r1 = r0 - d * (96 * 96);
    int hh = r1 / 96;
    int ww = r1 - hh * 96;
    int bp = b * 144 + (hh >> 3) * 12 + (ww >> 3);
    int l  = d * 64 + (hh & 7) * 8 + (ww & 7);
    unsigned short* hp = h + ((size_t)bp * 512 + l) * 192;
    hp[lane]       = f2bf(d0 * rs * g[lane]       + bsh[lane]);
    hp[lane + 64]  = f2bf(d1 * rs * g[lane + 64]  + bsh[lane + 64]);
    hp[lane + 128] = f2bf(d2 * rs * g[lane + 128] + bsh[lane + 128]);
}

// ---------------------------------------------------------------------------
// K5: LayerNorm(norm4) on bf16 y, natural layout -> xn4 bf16.
// ---------------------------------------------------------------------------
__global__ __launch_bounds__(256) void k_ln4b(const unsigned short* __restrict__ yb,
                                              const float* __restrict__ g,
                                              const float* __restrict__ bsh,
                                              unsigned short* __restrict__ xn) {
    int sub = threadIdx.x >> 5, tl = threadIdx.x & 31;
    size_t row = (size_t)blockIdx.x * 8 + sub;
    const unsigned int* rp = reinterpret_cast<const unsigned int*>(yb + row * 192);
    float v[6];
#pragma unroll
    for (int j = 0; j < 3; j++) {
        unsigned int w = rp[tl + 32 * j];
        v[2 * j]     = bf2f((unsigned short)(w & 0xffffu));
        v[2 * j + 1] = bf2f((unsigned short)(w >> 16));
    }
    float s = v[0] + v[1] + v[2] + v[3] + v[4] + v[5];
#pragma unroll
    for (int off = 1; off < 32; off <<= 1) s += __shfl_xor(s, off);
    float mean = s * (1.f / 192.f);
    float q = 0.f;
#pragma unroll
    for (int j = 0; j < 6; j++) { v[j] -= mean; q += v[j] * v[j]; }
#pragma unroll
    for (int off = 1; off < 32; off <<= 1) q += __shfl_xor(q, off);
    float rs = rsqrtf(q * (1.f / 192.f) + 1e-5f);
    unsigned int* op = reinterpret_cast<unsigned int*>(xn + row * 192);
#pragma unroll
    for (int j = 0; j < 3; j++) {
        int c = (tl + 32 * j) * 2;
        unsigned short lo = f2bf(v[2 * j]     * rs * g[c]     + bsh[c]);
        unsigned short hi = f2bf(v[2 * j + 1] * rs * g[c + 1] + bsh[c + 1]);
        op[tl + 32 * j] = ((unsigned int)hi << 16) | lo;
    }
}

// ---------------------------------------------------------------------------
// K2: 128x128-tile GEMM, dbuf + COUNTED-vmcnt pipeline (T3+T4 minimum):
//   stage(t+1) -> s_waitcnt vmcnt(8) -> s_barrier -> compute(t) -> s_barrier
// The 8 outstanding gl_lds of tile t+1 stay in flight ACROSS both barriers
// and the whole compute phase (never drained to 0 in the main loop).
// Each thread issues exactly 8 gl_lds per stage (4 A + 4 B), so vmcnt(8)
// waits precisely for tile t's loads. Raw s_barrier (no compiler vmcnt(0));
// sched_barrier(0) fences per rule #18.
// EPI 0: qkv -> qk (q scaled) + vt (v transposed, packed 8B)
// EPI 1: out_proj + window-reverse + x residual -> ybf bf16 (natural layout)
// EPI 2: fc1 + exact gelu -> hidden bf16
// EPI 3: fc2 + ybf residual -> out fp32 (d_out)
// ---------------------------------------------------------------------------
template <int EPI, int K>
__global__ __launch_bounds__(256) void k_gemm128(const unsigned short* __restrict__ A,
                                                 const unsigned short* __restrict__ Bw,
                                                 const float* __restrict__ bias,
                                                 unsigned short* __restrict__ outb,
                                                 unsigned short* __restrict__ vt,
                                                 float* __restrict__ outf,
                                                 const float* __restrict__ res,
                                                 const unsigned short* __restrict__ resb) {
    __shared__ unsigned short As[2][128 * 64];
    __shared__ unsigned short Bs[2][128 * 64];
    const int tid = threadIdx.x;
    // XCD-aware swizzle of the flat block id (nwg % 8 == 0)
    const int nwg = gridDim.x * gridDim.y;
    const int flat = blockIdx.y * gridDim.x + blockIdx.x;
    const int swz = (flat & 7) * (nwg >> 3) + (flat >> 3);
    const int bx = swz % gridDim.x, by = swz / gridDim.x;
    const int row0 = by * 128, col0 = bx * 128;
    const int wv = tid >> 6, lane = tid & 63, lr = lane & 15, lg = lane >> 4;
    const int wr = wv >> 1, wc = wv & 1;
    const int sr = lane >> 3, sc = lane & 7;     // staging: 8 rows x 8 chunks / inst
    f32x4 acc[4][4] = {};

    auto stage = [&](int t, int buf) {
        int k0 = t * 64;
#pragma unroll
        for (int i = 0; i < 4; i++) {
            int gq = wv * 4 + i;                 // 1KB group = rows [gq*8, gq*8+8)
            int r = gq * 8 + sr;
            int j = sc ^ (r & 7);                // swizzled source chunk
            gl_lds16(A + (size_t)(row0 + r) * K + k0 + j * 8, &As[buf][gq * 512]);
        }
#pragma unroll
        for (int i = 0; i < 4; i++) {
            int gq = wv * 4 + i;
            int r = gq * 8 + sr;
            int j = sc ^ (r & 7);
            gl_lds16(Bw + (size_t)(col0 + r) * K + k0 + j * 8, &Bs[buf][gq * 512]);
        }
    };

    const int NT = K / 64;
    stage(0, 0);
    for (int t = 0; t < NT; ++t) {
        int cur = t & 1;
        if (t + 1 < NT) {
            stage(t + 1, cur ^ 1);               // 16 outstanding
            asm volatile("s_waitcnt vmcnt(8)" ::: "memory");   // tile t landed
        } else {
            asm volatile("s_waitcnt vmcnt(0)" ::: "memory");
        }
        __builtin_amdgcn_sched_barrier(0);
        __builtin_amdgcn_s_barrier();            // raw: t+1 loads stay in flight
        __builtin_amdgcn_sched_barrier(0);
#pragma unroll
        for (int kk = 0; kk < 64; kk += 32) {
            bf16x8 af[4], bf[4];
#pragma unroll
            for (int m = 0; m < 4; m++) {
                int r = wr * 64 + m * 16 + lr;
                int j = ((kk >> 3) + lg) ^ (r & 7);
                af[m] = __builtin_bit_cast(bf16x8,
                    *reinterpret_cast<const u32x4*>(&As[cur][r * 64 + j * 8]));
            }
#pragma unroll
            for (int n = 0; n < 4; n++) {
                int r = wc * 64 + n * 16 + lr;
                int j = ((kk >> 3) + lg) ^ (r & 7);
                bf[n] = __builtin_bit_cast(bf16x8,
                    *reinterpret_cast<const u32x4*>(&Bs[cur][r * 64 + j * 8]));
            }
#pragma unroll
            for (int m = 0; m < 4; m++)
#pragma unroll
                for (int n = 0; n < 4; n++)
                    acc[m][n] = __builtin_amdgcn_mfma_f32_16x16x32_bf16(af[m], bf[n], acc[m][n], 0, 0, 0);
        }
        __builtin_amdgcn_sched_barrier(0);
        __builtin_amdgcn_s_barrier();            // readers done before buf reuse
        __builtin_amdgcn_sched_barrier(0);
    }

#pragma unroll
    for (int m = 0; m < 4; m++) {
#pragma unroll
        for (int n = 0; n < 4; n++) {
            int col  = col0 + wc * 64 + n * 16 + lr;
            int rowb = row0 + wr * 64 + m * 16 + lg * 4;
            if constexpr (EPI == 0) {
                if (col < 384) {
                    float b = bias[col];
                    float sc2 = (col < 192) ? 0.1020620726159658f : 1.f;  // 1/sqrt(96) on q
#pragma unroll
                    for (int rr = 0; rr < 4; rr++)
                        outb[(size_t)(rowb + rr) * 384 + col] = f2bf((acc[m][n][rr] + b) * sc2);
                } else if (col < 576) {
                    float b = bias[col];
                    int head = (col >= 480) ? 1 : 0;
                    int d = col - 384 - head * 96;
                    int bp = rowb >> 9, tok = rowb & 511;
                    u16x4 pk = { f2bf(acc[m][n][0] + b), f2bf(acc[m][n][1] + b),
                                 f2bf(acc[m][n][2] + b), f2bf(acc[m][n][3] + b) };
                    *reinterpret_cast<u16x4*>(vt + ((size_t)(bp * 2 + head) * 96 + d) * 512 + tok) = pk;
                }
            } else if constexpr (EPI == 1) {
                if (col < 192) {
                    float b = bias[col];
#pragma unroll
                    for (int rr = 0; rr < 4; rr++) {
                        int nrow = rowb + rr;
                        int bp = nrow >> 9, l = nrow & 511;
                        int bb = bp / 144, p = bp - bb * 144;
                        int hn = p / 12, wn = p - hn * 12;
                        int dn = l >> 6, t_ = l & 63;
                        size_t tok = ((size_t)((bb * 8 + dn) * 96 + hn * 8 + (t_ >> 3)) * 96 + wn * 8 + (t_ & 7));
                        size_t idx = tok * 192 + col;
                        outb[idx] = f2bf(res[idx] + acc[m][n][rr] + b);   // ybf bf16
                    }
                }
            } else if constexpr (EPI == 2) {
                float b = bias[col];
#pragma unroll
                for (int rr = 0; rr < 4; rr++) {
                    float v = acc[m][n][rr] + b;
                    float gz = 0.5f * v * (1.f + erff(v * 0.70710678118654752f));
                    outb[(size_t)(rowb + rr) * 768 + col] = f2bf(gz);
                }
            } else {
                if (col < 192) {
                    float b = bias[col];
#pragma unroll
                    for (int rr = 0; rr < 4; rr++) {
                        size_t idx = (size_t)(rowb + rr) * 192 + col;
                        outf[idx] = bf2f(resb[idx]) + acc[m][n][rr] + b;
                    }
                }
            }
        }
    }
}

// ---------------------------------------------------------------------------
// K3: block-causal attention, dnq-paired 8-wave WG (unchanged from round 4).
// ---------------------------------------------------------------------------
__global__ __launch_bounds__(512) void k_attn(const unsigned short* __restrict__ qk,
                                              const unsigned short* __restrict__ vt,
                                              unsigned short* __restrict__ aout) {
    __shared__ unsigned short Ks[64][104];
    __shared__ unsigned short Vs[96][72];
    __shared__ unsigned short Ps[8][16][72];

    int bid = (blockIdx.x & 7) * 288 + (blockIdx.x >> 3);   // 2304 % 8 == 0
    int bp = bid >> 3, rest = bid & 7, head = rest >> 2, pr = rest & 3;
    int tid = threadIdx.x, wv = tid >> 6, lane = tid & 63;
    int lr = lane & 15, lg = lane >> 4;
    int wq = wv & 3, wt = wv >> 2;
    int nk = 2 * pr + 2;

    size_t qrow0 = (size_t)bp * 512 + (size_t)(2 * pr + wt) * 64;
    const unsigned short* vbase = vt + (size_t)(bp * 2 + head) * 96 * 512;
    size_t krowb = (size_t)bp * 512;

    bf16x8 qf[3];
    {
        const unsigned short* qp = qk + (qrow0 + wq * 16 + lr) * 384 + head * 96 + lg * 8;
#pragma unroll
        for (int ks = 0; ks < 3; ks++)
            qf[ks] = __builtin_bit_cast(bf16x8, *reinterpret_cast<const u32x4*>(qp + ks * 32));
    }

    f32x4 o[6] = {};
    float m_ = -1e30f, lsum = 0.f;

    u32x4 sreg[3];
    auto issue = [&](int dnk) {
#pragma unroll
        for (int i = 0; i < 3; i++) {
            int c = tid + i * 512;
            if (c < 768) {
                int r = c / 12, cc = c - r * 12;
                sreg[i] = *reinterpret_cast<const u32x4*>(
                    qk + (krowb + dnk * 64 + r) * 384 + 192 + head * 96 + cc * 8);
            } else {
                int c2 = c - 768; int d = c2 >> 3, tb = c2 & 7;
                sreg[i] = *reinterpret_cast<const u32x4*>(
                    vbase + (size_t)d * 512 + dnk * 64 + tb * 8);
            }
        }
    };
    auto commit = [&]() {
#pragma unroll
        for (int i = 0; i < 3; i++) {
            int c = tid + i * 512;
            if (c < 768) {
                int r = c / 12, cc = c - r * 12;
                *reinterpret_cast<u32x4*>(&Ks[r][cc * 8]) = sreg[i];
            } else {
                int c2 = c - 768; int d = c2 >> 3, tb = c2 & 7;
                *reinterpret_cast<u32x4*>(&Vs[d][tb * 8]) = sreg[i];
            }
        }
    };

    issue(0);
    for (int dnk = 0; dnk < nk; ++dnk) {
        commit();
        __syncthreads();
        if (dnk + 1 < nk) issue(dnk + 1);
        if (wt == 1 || dnk < nk - 1) {
            f32x4 st[4] = {};
#pragma unroll
            for (int ks = 0; ks < 3; ks++) {
#pragma unroll
                for (int ct = 0; ct < 4; ct++) {
                    bf16x8 kf = __builtin_bit_cast(bf16x8,
                        *reinterpret_cast<const u32x4*>(&Ks[ct * 16 + lr][ks * 32 + lg * 8]));
                    st[ct] = __builtin_amdgcn_mfma_f32_16x16x32_bf16(kf, qf[ks], st[ct], 0, 0, 0);
                }
            }
            float mx = st[0][0];
#pragma unroll
            for (int ct = 0; ct < 4; ct++)
#pragma unroll
                for (int rr = 0; rr < 4; rr++) mx = fmaxf(mx, st[ct][rr]);
            mx = fmaxf(mx, __shfl_xor(mx, 16));
            mx = fmaxf(mx, __shfl_xor(mx, 32));
            float mnew = fmaxf(m_, mx);
            float corr = __expf(m_ - mnew);
            m_ = mnew;
            float ps = 0.f;
#pragma unroll
            for (int ct = 0; ct < 4; ct++) {
                u16x4 pk;
#pragma unroll
                for (int rr = 0; rr < 4; rr++) {
                    float pv = __expf(st[ct][rr] - mnew);
                    ps += pv;
                    pk[rr] = f2bf(pv);
                }
                *reinterpret_cast<u16x4*>(&Ps[wv][lr][ct * 16 + lg * 4]) = pk;
            }
            ps += __shfl_xor(ps, 16);
            ps += __shfl_xor(ps, 32);
            lsum = lsum * corr + ps;
#pragma unroll
            for (int rr = 0; rr < 4; rr++) {
                float cr = __shfl(corr, (lane & 48) | (lg * 4 + rr));
#pragma unroll
                for (int nf = 0; nf < 6; nf++) o[nf][rr] *= cr;
            }
#pragma unroll
            for (int kk = 0; kk < 2; kk++) {
                bf16x8 pf = __builtin_bit_cast(bf16x8,
                    *reinterpret_cast<const u32x4*>(&Ps[wv][lr][kk * 32 + lg * 8]));
#pragma unroll
                for (int nf = 0; nf < 6; nf++) {
                    bf16x8 vf = __builtin_bit_cast(bf16x8,
                        *reinterpret_cast<const u32x4*>(&Vs[nf * 16 + lr][kk * 32 + lg * 8]));
                    o[nf] = __builtin_amdgcn_mfma_f32_16x16x32_bf16(pf, vf, o[nf], 0, 0, 0);
                }
            }
        }
        __syncthreads();
    }

#pragma unroll
    for (int rr = 0; rr < 4; rr++) {
        float li = __shfl(lsum, (lane & 48) | (lg * 4 + rr));
        float inv = 1.f / li;
        size_t row = qrow0 + wq * 16 + lg * 4 + rr;
#pragma unroll
        for (int nf = 0; nf < 6; nf++)
            aout[row * 192 + head * 96 + nf * 16 + lr] = f2bf(o[nf][rr] * inv);
    }
}

// ---------------------------------------------------------------------------
// Launcher. ws arena (~340.8 MB):
//   [0, 113.2M)        qk bf16 [147456][384]   } hidden [147456][768]
//   [113.2M, 169.9M)   vt bf16 [576][96][512]  }   aliases [0, 226.5M)
//   [169.9M, 226.5M)   h  bf16 [147456][192]   }   at fc1/fc2 time
//   [226.5M, 283.1M)   attn bf16 ; xn4 aliases it after out_proj
//   [283.1M, 284.2M)   bf16 padded weights
//   [284.2M, 340.8M)   ybf bf16 [147456][192]  (x + attn residual)
// d_out written only by fc2 (fully rewritten each call => replay safe).
// ---------------------------------------------------------------------------
extern "C" void kernel_launch(void* const* d_in, const int* in_sizes, int n_in,
                              void* d_out, int out_size, void* d_ws, size_t ws_size,
                              hipStream_t stream) {
    const float* x    = (const float*)d_in[0];
    const float* n3g  = (const float*)d_in[1];
    const float* n3b  = (const float*)d_in[2];
    const float* wqkv = (const float*)d_in[3];
    const float* bqkv = (const float*)d_in[4];
    const float* wout = (const float*)d_in[5];
    const float* bout = (const float*)d_in[6];
    const float* n4g  = (const float*)d_in[7];
    const float* n4b  = (const float*)d_in[8];
    const float* wfc1 = (const float*)d_in[9];
    const float* bfc1 = (const float*)d_in[10];
    const float* wfc2 = (const float*)d_in[11];
    const float* bfc2 = (const float*)d_in[12];
    float* out = (float*)d_out;

    char* ws = (char*)d_ws;
    unsigned short* qk     = (unsigned short*)(ws + 0);
    unsigned short* vt     = (unsigned short*)(ws + 113246208);
    unsigned short* h      = (unsigned short*)(ws + 169869312);
    unsigned short* attn   = (unsigned short*)(ws + 226492416);
    unsigned short* xn4    = (unsigned short*)(ws + 226492416);   // alias attn
    unsigned short* hidden = (unsigned short*)(ws + 0);           // alias qk+vt+h
    unsigned short* wq_bf  = (unsigned short*)(ws + 283115520);
    unsigned short* wo_bf  = (unsigned short*)(ws + 283361280);
    unsigned short* w1_bf  = (unsigned short*)(ws + 283459584);
    unsigned short* w2_bf  = (unsigned short*)(ws + 283754496);
    unsigned short* ybf    = (unsigned short*)(ws + 284147712);

    k_wconv<<<2016, 256, 0, stream>>>(wqkv, wout, wfc1, wfc2, wq_bf, wo_bf, w1_bf, w2_bf);
    k_ln3<<<36864, 256, 0, stream>>>(x, n3g, n3b, h);
    k_gemm128<0, 192><<<dim3(5, 1152), 256, 0, stream>>>(h, wq_bf, bqkv, qk, vt, nullptr, nullptr, nullptr);
    k_attn<<<2304, 512, 0, stream>>>(qk, vt, attn);
    k_gemm128<1, 192><<<dim3(2, 1152), 256, 0, stream>>>(attn, wo_bf, bout, ybf, nullptr, nullptr, x, nullptr);
    k_ln4b<<<18432, 256, 0, stream>>>(ybf, n4g, n4b, xn4);
    k_gemm128<2, 192><<<dim3(6, 1152), 256, 0, stream>>>(xn4, w1_bf, bfc1, hidden, nullptr, nullptr, nullptr, nullptr);
    k_gemm128<3, 768><<<dim3(2, 1152), 256, 0, stream>>>(hidden, w2_bf, bfc2, nullptr, nullptr, out, nullptr, ybf);
}